// Round 6
// baseline (648.028 us; speedup 1.0000x reference)
//
#include <hip/hip_runtime.h>
#include <math.h>

#define XD 32
#define HD 128

typedef float f32x16 __attribute__((ext_vector_type(16)));
typedef int v2i __attribute__((ext_vector_type(2)));

#if __has_builtin(__builtin_amdgcn_cvt_pk_fp8_f32)
#define HAVE_CVT_FP8 1
#endif

// ---- scalar f32 -> e4m3fn (RNE), used by prep (and kernel fallback) ----
static __device__ __forceinline__ unsigned char f2e4m3(float f){
  if (!(f==f)) return 0x7F;
  unsigned u = __float_as_uint(f);
  unsigned s = (u>>24)&0x80;
  float a = fabsf(f);
  if (a >= 464.f) return (unsigned char)(s|0x7E);           // clamp to 448
  if (a < 0.0009765625f) return (unsigned char)s;            // < 2^-10 -> 0
  int e = (int)((u>>23)&0xFF) - 127;
  if (e < -6){                                               // subnormal, ulp=2^-9
    int m = (int)rintf(ldexpf(a, 9));
    if (m >= 8) return (unsigned char)(s|0x08);
    return (unsigned char)(s|(unsigned)m);
  }
  int m = (int)rintf(ldexpf(a, 3-e));                        // in [8,16]
  if (m == 16){ ++e; m = 8; }
  if (e > 8) return (unsigned char)(s|0x7E);
  return (unsigned char)(s | (unsigned)((e+7)<<3) | (unsigned)(m-8));
}

template<bool HI>
static __device__ __forceinline__ int cvtpk_fp8(float a, float b, int old){
#ifdef HAVE_CVT_FP8
  return __builtin_amdgcn_cvt_pk_fp8_f32(a, b, old, HI);
#else
  int w = (int)f2e4m3(a) | ((int)f2e4m3(b) << 8);
  return HI ? ((old & 0x0000FFFF) | (w << 16)) : ((old & (int)0xFFFF0000) | w);
#endif
}

// exchange halves: new_x[l] = l<32 ? x[l] : y[l-32]; new_y[l] = l<32 ? x[l+32] : y[l]
static __device__ __forceinline__ void plswap(int &x, int &y){
#if __has_builtin(__builtin_amdgcn_permlane32_swap)
  v2i r = __builtin_amdgcn_permlane32_swap(x, y, false, false);
  x = r[0]; y = r[1];
#else
  unsigned lane = threadIdx.x & 63u;
  int sx = __shfl_xor(x, 32, 64);
  int sy = __shfl_xor(y, 32, 64);
  int nx = (lane < 32) ? x : sy;
  int ny = (lane < 32) ? sx : y;
  x = nx; y = ny;
#endif
}

// One K=16 fp8 B-frag (as long) from a 32x32 f32 C tile, relu applied.
// C: feat=(r&3)+8*(r>>2)+4*half, batch=lane&31.  B: col=lane&31, k=(l>>5)*8+j (byte j).
template<int KT>
static __device__ __forceinline__ long c2b_kt(const f32x16 &c){
  int P0 = cvtpk_fp8<false>(fmaxf(c[8*KT+0],0.f), fmaxf(c[8*KT+1],0.f), 0);
  P0     = cvtpk_fp8<true >(fmaxf(c[8*KT+2],0.f), fmaxf(c[8*KT+3],0.f), P0);
  int P1 = cvtpk_fp8<false>(fmaxf(c[8*KT+4],0.f), fmaxf(c[8*KT+5],0.f), 0);
  P1     = cvtpk_fp8<true >(fmaxf(c[8*KT+6],0.f), fmaxf(c[8*KT+7],0.f), P1);
  plswap(P0, P1);
  return (long)(((unsigned long)(unsigned)P0) | ((unsigned long)(unsigned)P1 << 32));
}

static __device__ __forceinline__ void ld8(const float* __restrict__ p, float* dst){
  float4 a = *(const float4*)p, b = *(const float4*)(p+4);
  dst[0]=a.x; dst[1]=a.y; dst[2]=a.z; dst[3]=a.w;
  dst[4]=b.x; dst[5]=b.y; dst[6]=b.z; dst[7]=b.w;
}

// bias C-frag gather: element rg*4+q <- p[rg*8 + half*4 + q]
static __device__ __forceinline__ f32x16 load_bias16(const float* __restrict__ p, int half){
  f32x16 bv;
#pragma unroll
  for (int rg=0; rg<4; ++rg){
    const float4 t = *(const float4*)(p + rg*8 + half*4);
    bv[rg*4+0]=t.x; bv[rg*4+1]=t.y; bv[rg*4+2]=t.z; bv[rg*4+3]=t.w;
  }
  return bv;
}

// ---- prep: pack weights as fp8 A-frags (scaled); scaled biases as f32 ----
// A-frag (32x32x16 fp8): lane l holds row=l&31 (+fo*32), k=(l>>5)*8+j at byte j.
// scales: 8*Wi (z col at dead diag slot); 8*W1; 8*W2.
// bi8 = 8*bi ; b1s = 64*b1 ; b2s = 512*b2  (bias enters as first-MFMA C operand)
__global__ void prep(const float* __restrict__ Wi, const float* __restrict__ bi,
                     const float* __restrict__ W1, const float* __restrict__ b1,
                     const float* __restrict__ W2, const float* __restrict__ b2,
                     const float* __restrict__ M,
                     unsigned char* __restrict__ wip, unsigned char* __restrict__ w1p,
                     unsigned char* __restrict__ w2p, float* __restrict__ Mt,
                     float* __restrict__ bi8, float* __restrict__ b1s,
                     float* __restrict__ b2s){
  int b = (int)blockIdx.x;
  int l = (int)threadIdx.x;
  int h = l >> 5, cl = l & 31;
  if (b < 256){                       // wip: frag idx = i*8 + kt*4 + fo
    int i = b >> 3, kt = (b >> 2) & 1, fo = b & 3;
    int row = fo*32 + cl;
    unsigned char bytes[8];
#pragma unroll
    for (int j = 0; j < 8; ++j){
      int k = kt*16 + h*8 + j;
      int src = (k == i) ? XD : k;
      bytes[j] = f2e4m3(8.f * Wi[((size_t)i*HD + row)*(XD+1) + src]);
    }
    long v8; __builtin_memcpy(&v8, bytes, 8);
    *(long*)(wip + ((size_t)b*64 + l)*8) = v8;
  } else if (b < 320){                // w1p/w2p: frag idx = kt*4 + fo
    const float* W = (b < 288) ? W1 : W2;
    unsigned char* dp = (b < 288) ? w1p : w2p;
    int f = (b - 256) & 31, kt = f >> 2, fo = f & 3;
    int row = fo*32 + cl;
    unsigned char bytes[8];
#pragma unroll
    for (int j = 0; j < 8; ++j)
      bytes[j] = f2e4m3(8.f * W[(size_t)row*HD + kt*16 + h*8 + j]);
    long v8; __builtin_memcpy(&v8, bytes, 8);
    *(long*)(dp + ((size_t)f*64 + l)*8) = v8;
  } else if (b == 320){               // M transpose
#pragma unroll
    for (int t = 0; t < 16; ++t){
      int idx = t*64 + l;
      int i = idx >> 5, k = idx & 31;
      Mt[i*32 + k] = M[k*32 + i];
    }
  } else {                            // scaled biases
    for (int t = 0; t < 64; ++t){
      int idx = t*64 + l;
      bi8[idx] = 8.f * bi[idx];
    }
#pragma unroll
    for (int t = 0; t < 2; ++t){
      b1s[t*64 + l] = 64.f  * b1[t*64 + l];
      b2s[t*64 + l] = 512.f * b2[t*64 + l];
    }
  }
}

// ---- main kernel: 512 blocks x 256 threads (4 waves); wave owns 32 rows ----
// 2 waves/SIMD pinned; W1 resident in VGPR, W2 in LDS (shared per block).
__global__ __launch_bounds__(256) __attribute__((amdgpu_waves_per_eu(2, 2)))
void genkern(const float* __restrict__ x, const float* __restrict__ z,
             const float* __restrict__ wf, const float* __restrict__ bf,
             const unsigned char* __restrict__ wip, const unsigned char* __restrict__ w1p,
             const unsigned char* __restrict__ w2p, const float* __restrict__ Mt,
             const float* __restrict__ bi8, const float* __restrict__ b1s,
             const float* __restrict__ b2s, float* __restrict__ out)
{
  __shared__ long w2lds[2048];        // 16 KB: W2 fp8 A-frags, frag f at [f*64 + lane]

  const int tid  = (int)threadIdx.x;
  const int lane = tid & 63;
  const int wv   = tid >> 6;
  const int half = lane >> 5, col = lane & 31;
  const long rbase = (long)blockIdx.x * 128 + wv * 32;

  // fill W2 LDS copy (2048 longs / 256 threads = 8 each)
#pragma unroll
  for (int t = 0; t < 8; ++t)
    w2lds[t*256 + tid] = ((const long*)w2p)[t*256 + tid];

  // resident W1 frags (fp8): 8 kt x 4 fo
  long w1f[8][4];
#pragma unroll
  for (int kt = 0; kt < 8; ++kt)
#pragma unroll
    for (int fo = 0; fo < 4; ++fo)
      w1f[kt][fo] = *(const long*)(w1p + (((size_t)(kt*4+fo))*64 + lane)*8);

  // out-state: lane(half h) holds k = kt*16 + h*8 + j at slot kt*8+j
  float st[16];
#pragma unroll
  for (int kt = 0; kt < 2; ++kt)
    ld8(x + (rbase + col)*XD + kt*16 + half*8, &st[kt*8]);

  __syncthreads();

  // 1-step-ahead prefetch buffers (A=even steps, B=odd steps)
  long wifA[2][4], wifB[2][4];
  float zvA, zvB;
#pragma unroll
  for (int kt = 0; kt < 2; ++kt)
#pragma unroll
    for (int fo = 0; fo < 4; ++fo)
      wifA[kt][fo] = *(const long*)(wip + (((size_t)(0*8 + kt*4 + fo))*64 + lane)*8);
  zvA = z[(rbase + col)*XD + 0];

#pragma unroll 1
  for (int ii = 0; ii < XD; ii += 2){
#pragma unroll
    for (int sub = 0; sub < 2; ++sub){
      const int i = ii + sub;
      const long (&wif)[2][4] = sub ? wifB : wifA;
      const float zvv = sub ? zvB : zvA;
      long (&wifN)[2][4] = sub ? wifA : wifB;
      float &zvN = sub ? zvA : zvB;

      // prefetch step i+1 (wraps at 31 -> 0, harmless)
      {
        const int ip = (i + 1) & (XD - 1);
#pragma unroll
        for (int kt = 0; kt < 2; ++kt)
#pragma unroll
          for (int fo = 0; fo < 4; ++fo)
            wifN[kt][fo] = *(const long*)(wip + (((size_t)(ip*8 + kt*4 + fo))*64 + lane)*8);
        zvN = z[(rbase + col)*XD + ip];
      }

      // in-step loads (L1/L2-hot): bias C-frags, M column
      f32x16 bic[4];
#pragma unroll
      for (int fo = 0; fo < 4; ++fo)
        bic[fo] = load_bias16(bi8 + (size_t)i*HD + fo*32, half);

      float mtv[2][8];
#pragma unroll
      for (int kt = 0; kt < 2; ++kt)
        ld8(Mt + i*32 + kt*16 + half*8, &mtv[kt][0]);

      // x_masked B-frags from state (fp8 pack); z injected after
      int xbi[2][2];
#pragma unroll
      for (int kt = 0; kt < 2; ++kt)
#pragma unroll
        for (int d = 0; d < 2; ++d){
          float v0 = st[kt*8+4*d+0]*mtv[kt][4*d+0];
          float v1 = st[kt*8+4*d+1]*mtv[kt][4*d+1];
          float v2 = st[kt*8+4*d+2]*mtv[kt][4*d+2];
          float v3 = st[kt*8+4*d+3]*mtv[kt][4*d+3];
          int w = cvtpk_fp8<false>(v0, v1, 0);
          xbi[kt][d] = cvtpk_fp8<true>(v2, v3, w);
        }
      // z byte-splice at k==i
      const int hmi = (i>>3)&1;
      const bool hm = (half == hmi);
      {
        const int kti = i>>4, di = (i>>2)&1, sh = 8*(i&3);
        const int msk = ~(0xFF << sh);
        int pz = cvtpk_fp8<false>(zvv, 0.f, 0) & 0xFF;
        int ins = pz << sh;
#pragma unroll
        for (int kt = 0; kt < 2; ++kt)
#pragma unroll
          for (int d = 0; d < 2; ++d)
            if (kt == kti && d == di){
              int mod = (xbi[kt][d] & msk) | ins;
              xbi[kt][d] = hm ? mod : xbi[kt][d];
            }
      }
      long xb[2];
#pragma unroll
      for (int kt = 0; kt < 2; ++kt)
        xb[kt] = (long)(((unsigned long)(unsigned)xbi[kt][0]) |
                        ((unsigned long)(unsigned)xbi[kt][1] << 32));

      // input layer: K=32, bias as C of first MFMA
      f32x16 acc[4];
#pragma unroll
      for (int fo = 0; fo < 4; ++fo)
        acc[fo] = __builtin_amdgcn_mfma_f32_32x32x16_fp8_fp8(wif[0][fo], xb[0], bic[fo], 0,0,0);
#pragma unroll
      for (int fo = 0; fo < 4; ++fo)
        acc[fo] = __builtin_amdgcn_mfma_f32_32x32x16_fp8_fp8(wif[1][fo], xb[1], acc[fo], 0,0,0);

      // h1 -> fp8 B-frags
      long hb[8];
#pragma unroll
      for (int fo = 0; fo < 4; ++fo){
        hb[fo*2+0] = c2b_kt<0>(acc[fo]);
        hb[fo*2+1] = c2b_kt<1>(acc[fo]);
      }

      // layer 1: K=128, bias C-init (W1 from VGPR)
      f32x16 a2[4];
#pragma unroll
      for (int fo = 0; fo < 4; ++fo)
        a2[fo] = __builtin_amdgcn_mfma_f32_32x32x16_fp8_fp8(
                   w1f[0][fo], hb[0], load_bias16(b1s + fo*32, half), 0,0,0);
#pragma unroll
      for (int kt = 1; kt < 8; ++kt)
#pragma unroll
        for (int fo = 0; fo < 4; ++fo)
          a2[fo] = __builtin_amdgcn_mfma_f32_32x32x16_fp8_fp8(w1f[kt][fo], hb[kt], a2[fo], 0,0,0);

      // preload W2 kt=0 group from LDS while finishing c2b
      long wl[2][4];
#pragma unroll
      for (int fo = 0; fo < 4; ++fo)
        wl[0][fo] = w2lds[(0*4+fo)*64 + lane];

#pragma unroll
      for (int fo = 0; fo < 4; ++fo){
        hb[fo*2+0] = c2b_kt<0>(a2[fo]);
        hb[fo*2+1] = c2b_kt<1>(a2[fo]);
      }

      // layer 2: K=128, bias C-init (W2 from LDS, 2-deep rolling buffer)
      f32x16 a3[4];
#pragma unroll
      for (int fo = 0; fo < 4; ++fo)
        wl[1][fo] = w2lds[(1*4+fo)*64 + lane];
#pragma unroll
      for (int fo = 0; fo < 4; ++fo)
        a3[fo] = __builtin_amdgcn_mfma_f32_32x32x16_fp8_fp8(
                   wl[0][fo], hb[0], load_bias16(b2s + fo*32, half), 0,0,0);
#pragma unroll
      for (int kt = 1; kt < 8; ++kt){
#pragma unroll
        for (int fo = 0; fo < 4; ++fo)
          if (kt < 7)
            wl[(kt+1)&1][fo] = w2lds[((kt+1)*4+fo)*64 + lane];
#pragma unroll
        for (int fo = 0; fo < 4; ++fo)
          a3[fo] = __builtin_amdgcn_mfma_f32_32x32x16_fp8_fp8(wl[kt&1][fo], hb[kt], a3[fo], 0,0,0);
      }

      // epilogue (VALU): val = sigmoid((relu(a3) . wf)/512 + bf)   (a3 is 512x h3)
      float part = 0.f;
#pragma unroll
      for (int fo = 0; fo < 4; ++fo){
        const float* wp = wf + (size_t)i*HD + fo*32;
#pragma unroll
        for (int rg = 0; rg < 4; ++rg){
          const float4 t = *(const float4*)(wp + rg*8 + half*4);
          part += fmaxf(a3[fo][rg*4+0], 0.f) * t.x;
          part += fmaxf(a3[fo][rg*4+1], 0.f) * t.y;
          part += fmaxf(a3[fo][rg*4+2], 0.f) * t.z;
          part += fmaxf(a3[fo][rg*4+3], 0.f) * t.w;
        }
      }
      float tt = part + __shfl_xor(part, 32, 64);
      float val = 1.f/(1.f + __expf(-(tt*(1.f/512.f) + bf[i])));

      // state update: column i lives at slot (i>>4)*8+(i&7) on half (i>>3)&1
      const int slot_i = ((i>>4)<<3) | (i&7);
#pragma unroll
      for (int s = 0; s < 16; ++s)
        if (s == slot_i)
          st[s] = hm ? val : st[s];
    }
  }

  // write out
#pragma unroll
  for (int kt = 0; kt < 2; ++kt){
    float* p = out + (rbase + col)*XD + kt*16 + half*8;
    float4 a, b;
    a.x = st[kt*8+0]; a.y = st[kt*8+1]; a.z = st[kt*8+2]; a.w = st[kt*8+3];
    b.x = st[kt*8+4]; b.y = st[kt*8+5]; b.z = st[kt*8+6]; b.w = st[kt*8+7];
    *(float4*)p = a;
    *(float4*)(p+4) = b;
  }
}

extern "C" void kernel_launch(void* const* d_in, const int* in_sizes, int n_in,
                              void* d_out, int out_size, void* d_ws, size_t ws_size,
                              hipStream_t stream){
  (void)in_sizes; (void)n_in; (void)out_size; (void)ws_size;
  const float* x  = (const float*)d_in[0];
  const float* z  = (const float*)d_in[1];
  const float* M  = (const float*)d_in[2];
  const float* Wi = (const float*)d_in[3];
  const float* bi = (const float*)d_in[4];
  const float* wf = (const float*)d_in[5];
  const float* bf = (const float*)d_in[6];
  const float* W1 = (const float*)d_in[7];
  const float* b1 = (const float*)d_in[8];
  const float* W2 = (const float*)d_in[9];
  const float* b2 = (const float*)d_in[10];

  unsigned char* wip = (unsigned char*)d_ws;            // 256*512 = 131072
  unsigned char* w1p = wip + 131072;                    // 32*512 = 16384
  unsigned char* w2p = w1p + 16384;                     // 16384
  float*         Mt  = (float*)(w2p + 16384);           // 4096
  float*         bi8 = Mt + 1024;                       // 16384
  float*         b1s = bi8 + 4096;                      // 512
  float*         b2s = b1s + 128;                       // 512

  prep<<<dim3(322), dim3(64), 0, stream>>>(Wi, bi, W1, b1, W2, b2, M,
                                           wip, w1p, w2p, Mt, bi8, b1s, b2s);
  genkern<<<dim3(512), dim3(256), 0, stream>>>(x, z, wf, bf, wip, w1p, w2p, Mt,
                                               bi8, b1s, b2s, (float*)d_out);
}

// Round 7
// 531.831 us; speedup vs baseline: 1.2185x; 1.2185x over previous
//
#include <hip/hip_runtime.h>
#include <math.h>

#define XD 32
#define HD 128

typedef float f32x16 __attribute__((ext_vector_type(16)));
typedef int v2i __attribute__((ext_vector_type(2)));
typedef long lx2 __attribute__((ext_vector_type(2)));

#if __has_builtin(__builtin_amdgcn_cvt_pk_fp8_f32)
#define HAVE_CVT_FP8 1
#endif

// ---- scalar f32 -> e4m3fn (RNE), used by prep (and kernel fallback) ----
static __device__ __forceinline__ unsigned char f2e4m3(float f){
  if (!(f==f)) return 0x7F;
  unsigned u = __float_as_uint(f);
  unsigned s = (u>>24)&0x80;
  float a = fabsf(f);
  if (a >= 464.f) return (unsigned char)(s|0x7E);           // clamp to 448
  if (a < 0.0009765625f) return (unsigned char)s;            // < 2^-10 -> 0
  int e = (int)((u>>23)&0xFF) - 127;
  if (e < -6){                                               // subnormal, ulp=2^-9
    int m = (int)rintf(ldexpf(a, 9));
    if (m >= 8) return (unsigned char)(s|0x08);
    return (unsigned char)(s|(unsigned)m);
  }
  int m = (int)rintf(ldexpf(a, 3-e));                        // in [8,16]
  if (m == 16){ ++e; m = 8; }
  if (e > 8) return (unsigned char)(s|0x7E);
  return (unsigned char)(s | (unsigned)((e+7)<<3) | (unsigned)(m-8));
}

template<bool HI>
static __device__ __forceinline__ int cvtpk_fp8(float a, float b, int old){
#ifdef HAVE_CVT_FP8
  return __builtin_amdgcn_cvt_pk_fp8_f32(a, b, old, HI);
#else
  int w = (int)f2e4m3(a) | ((int)f2e4m3(b) << 8);
  return HI ? ((old & 0x0000FFFF) | (w << 16)) : ((old & (int)0xFFFF0000) | w);
#endif
}

// exchange halves across lane 32 boundary
static __device__ __forceinline__ void plswap(int &x, int &y){
#if __has_builtin(__builtin_amdgcn_permlane32_swap)
  v2i r = __builtin_amdgcn_permlane32_swap(x, y, false, false);
  x = r[0]; y = r[1];
#else
  unsigned lane = threadIdx.x & 63u;
  int sx = __shfl_xor(x, 32, 64);
  int sy = __shfl_xor(y, 32, 64);
  int nx = (lane < 32) ? x : sy;
  int ny = (lane < 32) ? sx : y;
  x = nx; y = ny;
#endif
}

// One K=16 fp8 B-frag (as long) from a 32x32 f32 C tile, relu applied.
template<int KT>
static __device__ __forceinline__ long c2b_kt(const f32x16 &c){
  int P0 = cvtpk_fp8<false>(fmaxf(c[8*KT+0],0.f), fmaxf(c[8*KT+1],0.f), 0);
  P0     = cvtpk_fp8<true >(fmaxf(c[8*KT+2],0.f), fmaxf(c[8*KT+3],0.f), P0);
  int P1 = cvtpk_fp8<false>(fmaxf(c[8*KT+4],0.f), fmaxf(c[8*KT+5],0.f), 0);
  P1     = cvtpk_fp8<true >(fmaxf(c[8*KT+6],0.f), fmaxf(c[8*KT+7],0.f), P1);
  plswap(P0, P1);
  return (long)(((unsigned long)(unsigned)P0) | ((unsigned long)(unsigned)P1 << 32));
}

static __device__ __forceinline__ void ld8(const float* __restrict__ p, float* dst){
  float4 a = *(const float4*)p, b = *(const float4*)(p+4);
  dst[0]=a.x; dst[1]=a.y; dst[2]=a.z; dst[3]=a.w;
  dst[4]=b.x; dst[5]=b.y; dst[6]=b.z; dst[7]=b.w;
}

// bias C-frag gather straight into an accumulator: elem rg*4+q <- p[rg*8+half*4+q]
static __device__ __forceinline__ f32x16 load_bias16(const float* __restrict__ p, int half){
  f32x16 bv;
#pragma unroll
  for (int rg=0; rg<4; ++rg){
    const float4 t = *(const float4*)(p + rg*8 + half*4);
    bv[rg*4+0]=t.x; bv[rg*4+1]=t.y; bv[rg*4+2]=t.z; bv[rg*4+3]=t.w;
  }
  return bv;
}

// ---- prep ----
// wip: A-frag idx i*8+kt*4+fo at [(f*64+l)*8]  (8*Wi, z col at dead diag slot)
// w1p/w2p: b128-friendly layout: frag(kt,fo) at [((kt*2+(fo>>1))*64+l)*16 + (fo&1)*8]
// bi8=8*bi, b1s=64*b1, b2s=512*b2 (C-operand biases); Mt = M^T
__global__ void prep(const float* __restrict__ Wi, const float* __restrict__ bi,
                     const float* __restrict__ W1, const float* __restrict__ b1,
                     const float* __restrict__ W2, const float* __restrict__ b2,
                     const float* __restrict__ M,
                     unsigned char* __restrict__ wip, unsigned char* __restrict__ w1p,
                     unsigned char* __restrict__ w2p, float* __restrict__ Mt,
                     float* __restrict__ bi8, float* __restrict__ b1s,
                     float* __restrict__ b2s){
  int b = (int)blockIdx.x;
  int l = (int)threadIdx.x;
  int h = l >> 5, cl = l & 31;
  if (b < 256){
    int i = b >> 3, kt = (b >> 2) & 1, fo = b & 3;
    int row = fo*32 + cl;
    unsigned char bytes[8];
#pragma unroll
    for (int j = 0; j < 8; ++j){
      int k = kt*16 + h*8 + j;
      int src = (k == i) ? XD : k;
      bytes[j] = f2e4m3(8.f * Wi[((size_t)i*HD + row)*(XD+1) + src]);
    }
    long v8; __builtin_memcpy(&v8, bytes, 8);
    *(long*)(wip + ((size_t)b*64 + l)*8) = v8;
  } else if (b < 320){
    const float* W = (b < 288) ? W1 : W2;
    unsigned char* dp = (b < 288) ? w1p : w2p;
    int f = (b - 256) & 31, kt = f >> 2, fo = f & 3;
    int row = fo*32 + cl;
    unsigned char bytes[8];
#pragma unroll
    for (int j = 0; j < 8; ++j)
      bytes[j] = f2e4m3(8.f * W[(size_t)row*HD + kt*16 + h*8 + j]);
    long v8; __builtin_memcpy(&v8, bytes, 8);
    *(long*)(dp + (((size_t)(kt*2 + (fo>>1))*64 + l)*16) + (fo&1)*8) = v8;
  } else if (b == 320){
#pragma unroll
    for (int t = 0; t < 16; ++t){
      int idx = t*64 + l;
      int i = idx >> 5, k = idx & 31;
      Mt[i*32 + k] = M[k*32 + i];
    }
  } else {
    for (int t = 0; t < 64; ++t){
      int idx = t*64 + l;
      bi8[idx] = 8.f * bi[idx];
    }
#pragma unroll
    for (int t = 0; t < 2; ++t){
      b1s[t*64 + l] = 64.f  * b1[t*64 + l];
      b2s[t*64 + l] = 512.f * b2[t*64 + l];
    }
  }
}

// ---- main kernel: 512 blocks x 256 threads; wave owns 32 rows; 2 waves/SIMD ----
// W1+W2 in LDS (shared per block); <=210 live regs per wave; no separate bias arrays.
__global__ void __launch_bounds__(256, 2)
genkern(const float* __restrict__ x, const float* __restrict__ z,
        const float* __restrict__ wf, const float* __restrict__ bf,
        const unsigned char* __restrict__ wip, const unsigned char* __restrict__ w1p,
        const unsigned char* __restrict__ w2p, const float* __restrict__ Mt,
        const float* __restrict__ bi8, const float* __restrict__ b1s,
        const float* __restrict__ b2s, float* __restrict__ out)
{
  __shared__ long wlds[4096];          // 32 KB: W1 at [0..2047], W2 at [2048..4095]

  const int tid  = (int)threadIdx.x;
  const int lane = tid & 63;
  const int wv   = tid >> 6;
  const int half = lane >> 5, col = lane & 31;
  const long rbase = (long)blockIdx.x * 128 + wv * 32;

  {
    const long* w1pl = (const long*)w1p;
    const long* w2pl = (const long*)w2p;
#pragma unroll
    for (int t = 0; t < 8; ++t)
      wlds[t*256 + tid] = w1pl[t*256 + tid];
#pragma unroll
    for (int t = 0; t < 8; ++t)
      wlds[2048 + t*256 + tid] = w2pl[t*256 + tid];
  }

  // out-state: lane(half h) holds k = kt*16 + h*8 + j at slot kt*8+j
  float st[16];
#pragma unroll
  for (int kt = 0; kt < 2; ++kt)
    ld8(x + (rbase + col)*XD + kt*16 + half*8, &st[kt*8]);

  __syncthreads();

  // 1-step-ahead prefetch buffers (A=even steps, B=odd steps)
  long wifA[2][4], wifB[2][4];
  float zvA, zvB;
#pragma unroll
  for (int kt = 0; kt < 2; ++kt)
#pragma unroll
    for (int fo = 0; fo < 4; ++fo)
      wifA[kt][fo] = *(const long*)(wip + (((size_t)(kt*4 + fo))*64 + lane)*8);
  zvA = z[(rbase + col)*XD + 0];

#pragma unroll 1
  for (int ii = 0; ii < XD; ii += 2){
#pragma unroll
    for (int sub = 0; sub < 2; ++sub){
      const int i = ii + sub;
      const long (&wif)[2][4] = sub ? wifB : wifA;
      const float zvv = sub ? zvB : zvA;
      long (&wifN)[2][4] = sub ? wifA : wifB;
      float &zvN = sub ? zvA : zvB;

      // prefetch step i+1 (wraps 31->0, harmless)
      {
        const int ip = (i + 1) & (XD - 1);
#pragma unroll
        for (int kt = 0; kt < 2; ++kt)
#pragma unroll
          for (int fo = 0; fo < 4; ++fo)
            wifN[kt][fo] = *(const long*)(wip + (((size_t)(ip*8 + kt*4 + fo))*64 + lane)*8);
        zvN = z[(rbase + col)*XD + ip];
      }

      // single accumulator array, reused by all 3 layers; bias loads are its init
      f32x16 acc[4];
#pragma unroll
      for (int fo = 0; fo < 4; ++fo)
        acc[fo] = load_bias16(bi8 + (size_t)i*HD + fo*32, half);

      float mtv[2][8];
#pragma unroll
      for (int kt = 0; kt < 2; ++kt)
        ld8(Mt + i*32 + kt*16 + half*8, &mtv[kt][0]);

      // x_masked B-frags from state (fp8 pack); z spliced after
      int xbi[2][2];
#pragma unroll
      for (int kt = 0; kt < 2; ++kt)
#pragma unroll
        for (int d = 0; d < 2; ++d){
          float v0 = st[kt*8+4*d+0]*mtv[kt][4*d+0];
          float v1 = st[kt*8+4*d+1]*mtv[kt][4*d+1];
          float v2 = st[kt*8+4*d+2]*mtv[kt][4*d+2];
          float v3 = st[kt*8+4*d+3]*mtv[kt][4*d+3];
          int w = cvtpk_fp8<false>(v0, v1, 0);
          xbi[kt][d] = cvtpk_fp8<true>(v2, v3, w);
        }
      const int hmi = (i>>3)&1;
      const bool hm = (half == hmi);
      {
        const int kti = i>>4, di = (i>>2)&1, sh = 8*(i&3);
        const int msk = ~(0xFF << sh);
        int pz = cvtpk_fp8<false>(zvv, 0.f, 0) & 0xFF;
        int ins = pz << sh;
#pragma unroll
        for (int kt = 0; kt < 2; ++kt)
#pragma unroll
          for (int d = 0; d < 2; ++d)
            if (kt == kti && d == di){
              int mod = (xbi[kt][d] & msk) | ins;
              xbi[kt][d] = hm ? mod : xbi[kt][d];
            }
      }
      long xb[2];
#pragma unroll
      for (int kt = 0; kt < 2; ++kt)
        xb[kt] = (long)(((unsigned long)(unsigned)xbi[kt][0]) |
                        ((unsigned long)(unsigned)xbi[kt][1] << 32));

      // input layer: K=32 (Wi frags from prefetched VGPRs)
#pragma unroll
      for (int fo = 0; fo < 4; ++fo)
        acc[fo] = __builtin_amdgcn_mfma_f32_32x32x16_fp8_fp8(wif[0][fo], xb[0], acc[fo], 0,0,0);
#pragma unroll
      for (int fo = 0; fo < 4; ++fo)
        acc[fo] = __builtin_amdgcn_mfma_f32_32x32x16_fp8_fp8(wif[1][fo], xb[1], acc[fo], 0,0,0);

      // h1 -> fp8 B-frags
      long hb[8];
#pragma unroll
      for (int fo = 0; fo < 4; ++fo){
        hb[fo*2+0] = c2b_kt<0>(acc[fo]);
        hb[fo*2+1] = c2b_kt<1>(acc[fo]);
      }

      // layer 1: K=128, W1 from LDS (2x b128 per kt, rolling), bias C-init
      {
        lx2 wa = *(const lx2*)&wlds[((0*2+0)*64 + lane)*2];
        lx2 wb = *(const lx2*)&wlds[((0*2+1)*64 + lane)*2];
#pragma unroll
        for (int fo = 0; fo < 4; ++fo)
          acc[fo] = load_bias16(b1s + fo*32, half);
#pragma unroll
        for (int kt = 0; kt < 8; ++kt){
          lx2 na, nb;
          if (kt < 7){
            na = *(const lx2*)&wlds[(((kt+1)*2+0)*64 + lane)*2];
            nb = *(const lx2*)&wlds[(((kt+1)*2+1)*64 + lane)*2];
          }
          acc[0] = __builtin_amdgcn_mfma_f32_32x32x16_fp8_fp8(wa[0], hb[kt], acc[0], 0,0,0);
          acc[1] = __builtin_amdgcn_mfma_f32_32x32x16_fp8_fp8(wa[1], hb[kt], acc[1], 0,0,0);
          acc[2] = __builtin_amdgcn_mfma_f32_32x32x16_fp8_fp8(wb[0], hb[kt], acc[2], 0,0,0);
          acc[3] = __builtin_amdgcn_mfma_f32_32x32x16_fp8_fp8(wb[1], hb[kt], acc[3], 0,0,0);
          wa = na; wb = nb;
        }
      }

#pragma unroll
      for (int fo = 0; fo < 4; ++fo){
        hb[fo*2+0] = c2b_kt<0>(acc[fo]);
        hb[fo*2+1] = c2b_kt<1>(acc[fo]);
      }

      // layer 2: K=128, W2 from LDS, bias C-init
      {
        lx2 wa = *(const lx2*)&wlds[2048 + ((0*2+0)*64 + lane)*2];
        lx2 wb = *(const lx2*)&wlds[2048 + ((0*2+1)*64 + lane)*2];
#pragma unroll
        for (int fo = 0; fo < 4; ++fo)
          acc[fo] = load_bias16(b2s + fo*32, half);
#pragma unroll
        for (int kt = 0; kt < 8; ++kt){
          lx2 na, nb;
          if (kt < 7){
            na = *(const lx2*)&wlds[2048 + (((kt+1)*2+0)*64 + lane)*2];
            nb = *(const lx2*)&wlds[2048 + (((kt+1)*2+1)*64 + lane)*2];
          }
          acc[0] = __builtin_amdgcn_mfma_f32_32x32x16_fp8_fp8(wa[0], hb[kt], acc[0], 0,0,0);
          acc[1] = __builtin_amdgcn_mfma_f32_32x32x16_fp8_fp8(wa[1], hb[kt], acc[1], 0,0,0);
          acc[2] = __builtin_amdgcn_mfma_f32_32x32x16_fp8_fp8(wb[0], hb[kt], acc[2], 0,0,0);
          acc[3] = __builtin_amdgcn_mfma_f32_32x32x16_fp8_fp8(wb[1], hb[kt], acc[3], 0,0,0);
          wa = na; wb = nb;
        }
      }

      // epilogue (VALU): val = sigmoid((relu(acc) . wf)/512 + bf)
      float part = 0.f;
#pragma unroll
      for (int fo = 0; fo < 4; ++fo){
        const float* wp = wf + (size_t)i*HD + fo*32;
#pragma unroll
        for (int rg = 0; rg < 4; ++rg){
          const float4 t = *(const float4*)(wp + rg*8 + half*4);
          part += fmaxf(acc[fo][rg*4+0], 0.f) * t.x;
          part += fmaxf(acc[fo][rg*4+1], 0.f) * t.y;
          part += fmaxf(acc[fo][rg*4+2], 0.f) * t.z;
          part += fmaxf(acc[fo][rg*4+3], 0.f) * t.w;
        }
      }
      float tt = part + __shfl_xor(part, 32, 64);
      float val = 1.f/(1.f + __expf(-(tt*(1.f/512.f) + bf[i])));

      const int slot_i = ((i>>4)<<3) | (i&7);
#pragma unroll
      for (int s = 0; s < 16; ++s)
        if (s == slot_i)
          st[s] = hm ? val : st[s];
    }
  }

  // write out
#pragma unroll
  for (int kt = 0; kt < 2; ++kt){
    float* p = out + (rbase + col)*XD + kt*16 + half*8;
    float4 a, b;
    a.x = st[kt*8+0]; a.y = st[kt*8+1]; a.z = st[kt*8+2]; a.w = st[kt*8+3];
    b.x = st[kt*8+4]; b.y = st[kt*8+5]; b.z = st[kt*8+6]; b.w = st[kt*8+7];
    *(float4*)p = a;
    *(float4*)(p+4) = b;
  }
}

extern "C" void kernel_launch(void* const* d_in, const int* in_sizes, int n_in,
                              void* d_out, int out_size, void* d_ws, size_t ws_size,
                              hipStream_t stream){
  (void)in_sizes; (void)n_in; (void)out_size; (void)ws_size;
  const float* x  = (const float*)d_in[0];
  const float* z  = (const float*)d_in[1];
  const float* M  = (const float*)d_in[2];
  const float* Wi = (const float*)d_in[3];
  const float* bi = (const float*)d_in[4];
  const float* wf = (const float*)d_in[5];
  const float* bf = (const float*)d_in[6];
  const float* W1 = (const float*)d_in[7];
  const float* b1 = (const float*)d_in[8];
  const float* W2 = (const float*)d_in[9];
  const float* b2 = (const float*)d_in[10];

  unsigned char* wip = (unsigned char*)d_ws;            // 256*512 = 131072
  unsigned char* w1p = wip + 131072;                    // 16384
  unsigned char* w2p = w1p + 16384;                     // 16384
  float*         Mt  = (float*)(w2p + 16384);           // 4096
  float*         bi8 = Mt + 1024;                       // 16384
  float*         b1s = bi8 + 4096;                      // 512
  float*         b2s = b1s + 128;                       // 512

  prep<<<dim3(322), dim3(64), 0, stream>>>(Wi, bi, W1, b1, W2, b2, M,
                                           wip, w1p, w2p, Mt, bi8, b1s, b2s);
  genkern<<<dim3(512), dim3(256), 0, stream>>>(x, z, wf, bf, wip, w1p, w2p, Mt,
                                               bi8, b1s, b2s, (float*)d_out);
}

// Round 8
// 301.227 us; speedup vs baseline: 2.1513x; 1.7655x over previous
//
#include <hip/hip_runtime.h>
#include <math.h>

#define XD 32
#define HD 128

typedef float f32x16 __attribute__((ext_vector_type(16)));
typedef int v2i __attribute__((ext_vector_type(2)));

#if __has_builtin(__builtin_amdgcn_cvt_pk_fp8_f32)
#define HAVE_CVT_FP8 1
#endif

// ---- scalar f32 -> e4m3fn (RNE), used by prep ----
static __device__ __forceinline__ unsigned char f2e4m3(float f){
  if (!(f==f)) return 0x7F;
  unsigned u = __float_as_uint(f);
  unsigned s = (u>>24)&0x80;
  float a = fabsf(f);
  if (a >= 464.f) return (unsigned char)(s|0x7E);           // clamp to 448
  if (a < 0.0009765625f) return (unsigned char)s;            // < 2^-10 -> 0
  int e = (int)((u>>23)&0xFF) - 127;
  if (e < -6){                                               // subnormal, ulp=2^-9
    int m = (int)rintf(ldexpf(a, 9));
    if (m >= 8) return (unsigned char)(s|0x08);
    return (unsigned char)(s|(unsigned)m);
  }
  int m = (int)rintf(ldexpf(a, 3-e));                        // in [8,16]
  if (m == 16){ ++e; m = 8; }
  if (e > 8) return (unsigned char)(s|0x7E);
  return (unsigned char)(s | (unsigned)((e+7)<<3) | (unsigned)(m-8));
}

template<bool HI>
static __device__ __forceinline__ int cvtpk_fp8(float a, float b, int old){
#ifdef HAVE_CVT_FP8
  return __builtin_amdgcn_cvt_pk_fp8_f32(a, b, old, HI);
#else
  int w = (int)f2e4m3(a) | ((int)f2e4m3(b) << 8);
  return HI ? ((old & 0x0000FFFF) | (w << 16)) : ((old & (int)0xFFFF0000) | w);
#endif
}

// exchange halves across lane-32 boundary
static __device__ __forceinline__ void plswap(int &x, int &y){
#if __has_builtin(__builtin_amdgcn_permlane32_swap)
  v2i r = __builtin_amdgcn_permlane32_swap(x, y, false, false);
  x = r[0]; y = r[1];
#else
  unsigned lane = threadIdx.x & 63u;
  int sx = __shfl_xor(x, 32, 64);
  int sy = __shfl_xor(y, 32, 64);
  int nx = (lane < 32) ? x : sy;
  int ny = (lane < 32) ? sx : y;
  x = nx; y = ny;
#endif
}

// One K=16 fp8 B-frag (as long) from a 32x32 f32 C tile, relu applied.
template<int KT>
static __device__ __forceinline__ long c2b_kt(const f32x16 &c){
  int P0 = cvtpk_fp8<false>(fmaxf(c[8*KT+0],0.f), fmaxf(c[8*KT+1],0.f), 0);
  P0     = cvtpk_fp8<true >(fmaxf(c[8*KT+2],0.f), fmaxf(c[8*KT+3],0.f), P0);
  int P1 = cvtpk_fp8<false>(fmaxf(c[8*KT+4],0.f), fmaxf(c[8*KT+5],0.f), 0);
  P1     = cvtpk_fp8<true >(fmaxf(c[8*KT+6],0.f), fmaxf(c[8*KT+7],0.f), P1);
  plswap(P0, P1);
  return (long)(((unsigned long)(unsigned)P0) | ((unsigned long)(unsigned)P1 << 32));
}

static __device__ __forceinline__ void ld8(const float* __restrict__ p, float* dst){
  float4 a = *(const float4*)p, b = *(const float4*)(p+4);
  dst[0]=a.x; dst[1]=a.y; dst[2]=a.z; dst[3]=a.w;
  dst[4]=b.x; dst[5]=b.y; dst[6]=b.z; dst[7]=b.w;
}

// bias C-frag gather straight into accumulator: elem rg*4+q <- p[rg*8+half*4+q]
static __device__ __forceinline__ f32x16 load_bias16(const float* __restrict__ p, int half){
  f32x16 bv;
#pragma unroll
  for (int rg=0; rg<4; ++rg){
    const float4 t = *(const float4*)(p + rg*8 + half*4);
    bv[rg*4+0]=t.x; bv[rg*4+1]=t.y; bv[rg*4+2]=t.z; bv[rg*4+3]=t.w;
  }
  return bv;
}

// ---- prep: pack weights as fp8 A-frags (scaled); scaled biases as f32 ----
// A-frag (32x32x16 fp8): lane l holds row=l&31 (+fo*32), k=(l>>5)*8+j at byte j.
// scales: 8*Wi (z col at dead diag slot); 8*W1; 8*W2.
// bi8 = 8*bi ; b1s = 64*b1 ; b2s = 512*b2  (bias enters as first-MFMA C operand)
__global__ void prep(const float* __restrict__ Wi, const float* __restrict__ bi,
                     const float* __restrict__ W1, const float* __restrict__ b1,
                     const float* __restrict__ W2, const float* __restrict__ b2,
                     const float* __restrict__ M,
                     unsigned char* __restrict__ wip, unsigned char* __restrict__ w1p,
                     unsigned char* __restrict__ w2p, float* __restrict__ Mt,
                     float* __restrict__ bi8, float* __restrict__ b1s,
                     float* __restrict__ b2s){
  int b = (int)blockIdx.x;
  int l = (int)threadIdx.x;
  int h = l >> 5, cl = l & 31;
  if (b < 256){                       // wip: frag idx = i*8 + kt*4 + fo
    int i = b >> 3, kt = (b >> 2) & 1, fo = b & 3;
    int row = fo*32 + cl;
    unsigned char bytes[8];
#pragma unroll
    for (int j = 0; j < 8; ++j){
      int k = kt*16 + h*8 + j;
      int src = (k == i) ? XD : k;
      bytes[j] = f2e4m3(8.f * Wi[((size_t)i*HD + row)*(XD+1) + src]);
    }
    long v8; __builtin_memcpy(&v8, bytes, 8);
    *(long*)(wip + ((size_t)b*64 + l)*8) = v8;
  } else if (b < 320){                // w1p/w2p: frag idx = kt*4 + fo
    const float* W = (b < 288) ? W1 : W2;
    unsigned char* dp = (b < 288) ? w1p : w2p;
    int f = (b - 256) & 31, kt = f >> 2, fo = f & 3;
    int row = fo*32 + cl;
    unsigned char bytes[8];
#pragma unroll
    for (int j = 0; j < 8; ++j)
      bytes[j] = f2e4m3(8.f * W[(size_t)row*HD + kt*16 + h*8 + j]);
    long v8; __builtin_memcpy(&v8, bytes, 8);
    *(long*)(dp + ((size_t)f*64 + l)*8) = v8;
  } else if (b == 320){               // M transpose
#pragma unroll
    for (int t = 0; t < 16; ++t){
      int idx = t*64 + l;
      int i = idx >> 5, k = idx & 31;
      Mt[i*32 + k] = M[k*32 + i];
    }
  } else {                            // scaled biases
    for (int t = 0; t < 64; ++t){
      int idx = t*64 + l;
      bi8[idx] = 8.f * bi[idx];
    }
#pragma unroll
    for (int t = 0; t < 2; ++t){
      b1s[t*64 + l] = 64.f  * b1[t*64 + l];
      b2s[t*64 + l] = 512.f * b2[t*64 + l];
    }
  }
}

// pack one tile's x_masked B-frags (fp8) from state, with z spliced at k==i
static __device__ __forceinline__ void pack_xb(const float (&st)[16], const float (&mtv)[16],
                                               float zvv, int i, bool hm, long (&xb)[2]){
  int xbi[2][2];
#pragma unroll
  for (int kt = 0; kt < 2; ++kt)
#pragma unroll
    for (int d = 0; d < 2; ++d){
      float v0 = st[kt*8+4*d+0]*mtv[kt*8+4*d+0];
      float v1 = st[kt*8+4*d+1]*mtv[kt*8+4*d+1];
      float v2 = st[kt*8+4*d+2]*mtv[kt*8+4*d+2];
      float v3 = st[kt*8+4*d+3]*mtv[kt*8+4*d+3];
      int w = cvtpk_fp8<false>(v0, v1, 0);
      xbi[kt][d] = cvtpk_fp8<true>(v2, v3, w);
    }
  const int kti = i>>4, di = (i>>2)&1, sh = 8*(i&3);
  const int msk = ~(0xFF << sh);
  int pz = cvtpk_fp8<false>(zvv, 0.f, 0) & 0xFF;
  int ins = pz << sh;
#pragma unroll
  for (int kt = 0; kt < 2; ++kt)
#pragma unroll
    for (int d = 0; d < 2; ++d)
      if (kt == kti && d == di){
        int mod = (xbi[kt][d] & msk) | ins;
        xbi[kt][d] = hm ? mod : xbi[kt][d];
      }
#pragma unroll
  for (int kt = 0; kt < 2; ++kt)
    xb[kt] = (long)(((unsigned long)(unsigned)xbi[kt][0]) |
                    ((unsigned long)(unsigned)xbi[kt][1] << 32));
}

// epilogue: val = sigmoid((relu(acc).wf)/512 + bf); update state slot
static __device__ __forceinline__ void epi(const f32x16 (&acc)[4], const float* __restrict__ wp0,
                                           float bfv, int half, bool hm, int slot_i,
                                           float (&st)[16]){
  float part = 0.f;
#pragma unroll
  for (int fo = 0; fo < 4; ++fo){
    const float* wp = wp0 + fo*32;
#pragma unroll
    for (int rg = 0; rg < 4; ++rg){
      const float4 t = *(const float4*)(wp + rg*8 + half*4);
      part += fmaxf(acc[fo][rg*4+0], 0.f) * t.x;
      part += fmaxf(acc[fo][rg*4+1], 0.f) * t.y;
      part += fmaxf(acc[fo][rg*4+2], 0.f) * t.z;
      part += fmaxf(acc[fo][rg*4+3], 0.f) * t.w;
    }
  }
  float tt = part + __shfl_xor(part, 32, 64);
  float val = 1.f/(1.f + __expf(-(tt*(1.f/512.f) + bfv)));
#pragma unroll
  for (int s = 0; s < 16; ++s)
    if (s == slot_i)
      st[s] = hm ? val : st[s];
}

// ---- main kernel: 1024 blocks x 64 threads; 2 batch tiles/wave, SKEWED; 1 wave/SIMD ----
// All weights VGPR-resident; tile B runs one phase behind tile A so every c2b/epilogue
// (VALU) overlaps the other tile's 32-MFMA cluster in the matrix pipe.
__global__ void __launch_bounds__(64, 1)
genkern(const float* __restrict__ x, const float* __restrict__ z,
        const float* __restrict__ wf, const float* __restrict__ bf,
        const unsigned char* __restrict__ wip, const unsigned char* __restrict__ w1p,
        const unsigned char* __restrict__ w2p, const float* __restrict__ Mt,
        const float* __restrict__ bi8, const float* __restrict__ b1s,
        const float* __restrict__ b2s, float* __restrict__ out)
{
  const int lane = (int)threadIdx.x;
  const int half = lane >> 5, col = lane & 31;
  const long rbase = (long)blockIdx.x * 64;

  // resident weight frags (fp8): 8 kt x 4 fo each
  long w1f[8][4], w2f[8][4];
#pragma unroll
  for (int kt = 0; kt < 8; ++kt)
#pragma unroll
    for (int fo = 0; fo < 4; ++fo){
      w1f[kt][fo] = *(const long*)(w1p + (((size_t)(kt*4+fo))*64 + lane)*8);
      w2f[kt][fo] = *(const long*)(w2p + (((size_t)(kt*4+fo))*64 + lane)*8);
    }

  // out-state per tile: lane(half h) holds k = kt*16 + h*8 + j at slot kt*8+j
  float stA[16], stB[16];
#pragma unroll
  for (int kt = 0; kt < 2; ++kt){
    ld8(x + (rbase + col)*XD + kt*16 + half*8,      &stA[kt*8]);
    ld8(x + (rbase + 32 + col)*XD + kt*16 + half*8, &stB[kt*8]);
  }

  // 1-step-ahead prefetch (parity buffers): Wi frags shared by both tiles; z per tile
  long wifP[2][2][4];
  float zAP[2], zBP[2];
#pragma unroll
  for (int kt = 0; kt < 2; ++kt)
#pragma unroll
    for (int fo = 0; fo < 4; ++fo)
      wifP[0][kt][fo] = *(const long*)(wip + (((size_t)(kt*4 + fo))*64 + lane)*8);
  zAP[0] = z[(rbase + col)*XD + 0];
  zBP[0] = z[(rbase + 32 + col)*XD + 0];

#pragma unroll 1
  for (int ii = 0; ii < XD; ii += 2){
#pragma unroll
    for (int sub = 0; sub < 2; ++sub){
      const int i = ii + sub;
      const int par = sub, npar = sub ^ 1;

      // prefetch step i+1 (wraps 31->0, harmless)
      {
        const int ip = (i + 1) & (XD - 1);
#pragma unroll
        for (int kt = 0; kt < 2; ++kt)
#pragma unroll
          for (int fo = 0; fo < 4; ++fo)
            wifP[npar][kt][fo] = *(const long*)(wip + (((size_t)(ip*8 + kt*4 + fo))*64 + lane)*8);
        zAP[npar] = z[(rbase + col)*XD + ip];
        zBP[npar] = z[(rbase + 32 + col)*XD + ip];
      }

      float mtv[16];
#pragma unroll
      for (int kt = 0; kt < 2; ++kt)
        ld8(Mt + i*32 + kt*16 + half*8, &mtv[kt*8]);

      const int hmi = (i>>3)&1;
      const bool hm = (half == hmi);
      const int slot_i = ((i>>4)<<3) | (i&7);

      long xbA[2], xbB[2];
      pack_xb(stA, mtv, zAP[par], i, hm, xbA);
      pack_xb(stB, mtv, zBP[par], i, hm, xbB);

      // ---- input layer (both tiles; short, 8+8 MFMA), bias C-init ----
      f32x16 accA[4], accB[4];
#pragma unroll
      for (int fo = 0; fo < 4; ++fo)
        accA[fo] = load_bias16(bi8 + (size_t)i*HD + fo*32, half);
#pragma unroll
      for (int fo = 0; fo < 4; ++fo)
        accB[fo] = load_bias16(bi8 + (size_t)i*HD + fo*32, half);
#pragma unroll
      for (int fo = 0; fo < 4; ++fo)
        accA[fo] = __builtin_amdgcn_mfma_f32_32x32x16_fp8_fp8(wifP[par][0][fo], xbA[0], accA[fo], 0,0,0);
#pragma unroll
      for (int fo = 0; fo < 4; ++fo)
        accA[fo] = __builtin_amdgcn_mfma_f32_32x32x16_fp8_fp8(wifP[par][1][fo], xbA[1], accA[fo], 0,0,0);
#pragma unroll
      for (int fo = 0; fo < 4; ++fo)
        accB[fo] = __builtin_amdgcn_mfma_f32_32x32x16_fp8_fp8(wifP[par][0][fo], xbB[0], accB[fo], 0,0,0);
#pragma unroll
      for (int fo = 0; fo < 4; ++fo)
        accB[fo] = __builtin_amdgcn_mfma_f32_32x32x16_fp8_fp8(wifP[par][1][fo], xbB[1], accB[fo], 0,0,0);

      // ---- skewed pipeline ----
      long hbA[8], hbB[8];

      // c2b1(A) ; issue L1(A)
#pragma unroll
      for (int fo = 0; fo < 4; ++fo){
        hbA[fo*2+0] = c2b_kt<0>(accA[fo]);
        hbA[fo*2+1] = c2b_kt<1>(accA[fo]);
      }
#pragma unroll
      for (int fo = 0; fo < 4; ++fo)
        accA[fo] = load_bias16(b1s + fo*32, half);
#pragma unroll
      for (int kt = 0; kt < 8; ++kt)
#pragma unroll
        for (int fo = 0; fo < 4; ++fo)
          accA[fo] = __builtin_amdgcn_mfma_f32_32x32x16_fp8_fp8(w1f[kt][fo], hbA[kt], accA[fo], 0,0,0);

      // c2b1(B) overlaps L1(A); issue L1(B)
#pragma unroll
      for (int fo = 0; fo < 4; ++fo){
        hbB[fo*2+0] = c2b_kt<0>(accB[fo]);
        hbB[fo*2+1] = c2b_kt<1>(accB[fo]);
      }
#pragma unroll
      for (int fo = 0; fo < 4; ++fo)
        accB[fo] = load_bias16(b1s + fo*32, half);
#pragma unroll
      for (int kt = 0; kt < 8; ++kt)
#pragma unroll
        for (int fo = 0; fo < 4; ++fo)
          accB[fo] = __builtin_amdgcn_mfma_f32_32x32x16_fp8_fp8(w1f[kt][fo], hbB[kt], accB[fo], 0,0,0);

      // c2b2(A) overlaps L1(B); issue L2(A)
#pragma unroll
      for (int fo = 0; fo < 4; ++fo){
        hbA[fo*2+0] = c2b_kt<0>(accA[fo]);
        hbA[fo*2+1] = c2b_kt<1>(accA[fo]);
      }
#pragma unroll
      for (int fo = 0; fo < 4; ++fo)
        accA[fo] = load_bias16(b2s + fo*32, half);
#pragma unroll
      for (int kt = 0; kt < 8; ++kt)
#pragma unroll
        for (int fo = 0; fo < 4; ++fo)
          accA[fo] = __builtin_amdgcn_mfma_f32_32x32x16_fp8_fp8(w2f[kt][fo], hbA[kt], accA[fo], 0,0,0);

      // c2b2(B) overlaps L2(A); issue L2(B)
#pragma unroll
      for (int fo = 0; fo < 4; ++fo){
        hbB[fo*2+0] = c2b_kt<0>(accB[fo]);
        hbB[fo*2+1] = c2b_kt<1>(accB[fo]);
      }
#pragma unroll
      for (int fo = 0; fo < 4; ++fo)
        accB[fo] = load_bias16(b2s + fo*32, half);
#pragma unroll
      for (int kt = 0; kt < 8; ++kt)
#pragma unroll
        for (int fo = 0; fo < 4; ++fo)
          accB[fo] = __builtin_amdgcn_mfma_f32_32x32x16_fp8_fp8(w2f[kt][fo], hbB[kt], accB[fo], 0,0,0);

      // epilogues: epi(A) overlaps L2(B)
      epi(accA, wf + (size_t)i*HD, bf[i], half, hm, slot_i, stA);
      epi(accB, wf + (size_t)i*HD, bf[i], half, hm, slot_i, stB);
    }
  }

  // write out both tiles
#pragma unroll
  for (int kt = 0; kt < 2; ++kt){
    float* pA = out + (rbase + col)*XD + kt*16 + half*8;
    float* pB = out + (rbase + 32 + col)*XD + kt*16 + half*8;
    float4 a, b;
    a.x = stA[kt*8+0]; a.y = stA[kt*8+1]; a.z = stA[kt*8+2]; a.w = stA[kt*8+3];
    b.x = stA[kt*8+4]; b.y = stA[kt*8+5]; b.z = stA[kt*8+6]; b.w = stA[kt*8+7];
    *(float4*)pA = a; *(float4*)(pA+4) = b;
    a.x = stB[kt*8+0]; a.y = stB[kt*8+1]; a.z = stB[kt*8+2]; a.w = stB[kt*8+3];
    b.x = stB[kt*8+4]; b.y = stB[kt*8+5]; b.z = stB[kt*8+6]; b.w = stB[kt*8+7];
    *(float4*)pB = a; *(float4*)(pB+4) = b;
  }
}

extern "C" void kernel_launch(void* const* d_in, const int* in_sizes, int n_in,
                              void* d_out, int out_size, void* d_ws, size_t ws_size,
                              hipStream_t stream){
  (void)in_sizes; (void)n_in; (void)out_size; (void)ws_size;
  const float* x  = (const float*)d_in[0];
  const float* z  = (const float*)d_in[1];
  const float* M  = (const float*)d_in[2];
  const float* Wi = (const float*)d_in[3];
  const float* bi = (const float*)d_in[4];
  const float* wf = (const float*)d_in[5];
  const float* bf = (const float*)d_in[6];
  const float* W1 = (const float*)d_in[7];
  const float* b1 = (const float*)d_in[8];
  const float* W2 = (const float*)d_in[9];
  const float* b2 = (const float*)d_in[10];

  unsigned char* wip = (unsigned char*)d_ws;            // 256*512 = 131072
  unsigned char* w1p = wip + 131072;                    // 16384
  unsigned char* w2p = w1p + 16384;                     // 16384
  float*         Mt  = (float*)(w2p + 16384);           // 4096
  float*         bi8 = Mt + 1024;                       // 16384
  float*         b1s = bi8 + 4096;                      // 512
  float*         b2s = b1s + 128;                       // 512

  prep<<<dim3(322), dim3(64), 0, stream>>>(Wi, bi, W1, b1, W2, b2, M,
                                           wip, w1p, w2p, Mt, bi8, b1s, b2s);
  genkern<<<dim3(1024), dim3(64), 0, stream>>>(x, z, wf, bf, wip, w1p, w2p, Mt,
                                               bi8, b1s, b2s, (float*)d_out);
}

// Round 9
// 168.103 us; speedup vs baseline: 3.8550x; 1.7919x over previous
//
#include <hip/hip_runtime.h>
#include <math.h>

#define XD 32
#define HD 128

typedef float f32x16 __attribute__((ext_vector_type(16)));
typedef int v2i __attribute__((ext_vector_type(2)));
typedef int i32x8 __attribute__((ext_vector_type(8)));

#if __has_builtin(__builtin_amdgcn_cvt_pk_fp8_f32)
#define HAVE_CVT_FP8 1
#endif

// ---- scalar f32 -> e4m3fn (RNE), used by prep ----
static __device__ __forceinline__ unsigned char f2e4m3(float f){
  if (!(f==f)) return 0x7F;
  unsigned u = __float_as_uint(f);
  unsigned s = (u>>24)&0x80;
  float a = fabsf(f);
  if (a >= 464.f) return (unsigned char)(s|0x7E);           // clamp to 448
  if (a < 0.0009765625f) return (unsigned char)s;            // < 2^-10 -> 0
  int e = (int)((u>>23)&0xFF) - 127;
  if (e < -6){                                               // subnormal, ulp=2^-9
    int m = (int)rintf(ldexpf(a, 9));
    if (m >= 8) return (unsigned char)(s|0x08);
    return (unsigned char)(s|(unsigned)m);
  }
  int m = (int)rintf(ldexpf(a, 3-e));                        // in [8,16]
  if (m == 16){ ++e; m = 8; }
  if (e > 8) return (unsigned char)(s|0x7E);
  return (unsigned char)(s | (unsigned)((e+7)<<3) | (unsigned)(m-8));
}

template<bool HI>
static __device__ __forceinline__ int cvtpk_fp8(float a, float b, int old){
#ifdef HAVE_CVT_FP8
  return __builtin_amdgcn_cvt_pk_fp8_f32(a, b, old, HI);
#else
  int w = (int)f2e4m3(a) | ((int)f2e4m3(b) << 8);
  return HI ? ((old & 0x0000FFFF) | (w << 16)) : ((old & (int)0xFFFF0000) | w);
#endif
}

// exchange halves across lane-32 boundary:
// x'[l<32]=x[l], x'[l>=32]=y[l-32] ; y'[l<32]=x[l+32], y'[l>=32]=y[l]
static __device__ __forceinline__ void plswap(int &x, int &y){
#if __has_builtin(__builtin_amdgcn_permlane32_swap)
  v2i r = __builtin_amdgcn_permlane32_swap(x, y, false, false);
  x = r[0]; y = r[1];
#else
  unsigned lane = threadIdx.x & 63u;
  int sx = __shfl_xor(x, 32, 64);
  int sy = __shfl_xor(y, 32, 64);
  int nx = (lane < 32) ? x : sy;
  int ny = (lane < 32) ? sx : y;
  x = nx; y = ny;
#endif
}

// Build one MX K=64 B-frag from two 32x32 f32 C tiles (relu applied).
// ca = tile feeding k-block 0..31 (h0 lanes), cb = tile for k 32..63 (h1 lanes).
// B layout (32x32x64 f8f6f4): col=lane&31, k=(lane>>5)*32 + byte_j.
static __device__ __forceinline__ i32x8 c2mx(const f32x16 &ca, const f32x16 &cb){
  i32x8 fr;
#pragma unroll
  for (int q = 0; q < 4; ++q){
    int x = cvtpk_fp8<false>(fmaxf(ca[q*4+0],0.f), fmaxf(ca[q*4+1],0.f), 0);
    x     = cvtpk_fp8<true >(fmaxf(ca[q*4+2],0.f), fmaxf(ca[q*4+3],0.f), x);
    int y = cvtpk_fp8<false>(fmaxf(cb[q*4+0],0.f), fmaxf(cb[q*4+1],0.f), 0);
    y     = cvtpk_fp8<true >(fmaxf(cb[q*4+2],0.f), fmaxf(cb[q*4+3],0.f), y);
    plswap(x, y);
    fr[q*2]   = x;   // h0: own 4 feats (8q..8q+3) | h1: partner feats of cb
    fr[q*2+1] = y;   // h0: partner feats (8q+4..) | h1: own feats of cb
  }
  return fr;
}

// MX-scaled MFMA, fp8 e4m3 both operands, all scales = 1.0 (e8m0 = 127)
static __device__ __forceinline__ f32x16 mfma_mx(i32x8 a, i32x8 b, f32x16 c){
  return __builtin_amdgcn_mfma_scale_f32_32x32x64_f8f6f4(
           a, b, c, 0, 0, 0, 0x7F7F7F7F, 0, 0x7F7F7F7F);
}

static __device__ __forceinline__ void ld8(const float* __restrict__ p, float* dst){
  float4 a = *(const float4*)p, b = *(const float4*)(p+4);
  dst[0]=a.x; dst[1]=a.y; dst[2]=a.z; dst[3]=a.w;
  dst[4]=b.x; dst[5]=b.y; dst[6]=b.z; dst[7]=b.w;
}

// bias C-frag gather straight into accumulator: elem rg*4+q <- p[rg*8+half*4+q]
static __device__ __forceinline__ f32x16 load_bias16(const float* __restrict__ p, int half){
  f32x16 bv;
#pragma unroll
  for (int rg=0; rg<4; ++rg){
    const float4 t = *(const float4*)(p + rg*8 + half*4);
    bv[rg*4+0]=t.x; bv[rg*4+1]=t.y; bv[rg*4+2]=t.z; bv[rg*4+3]=t.w;
  }
  return bv;
}

// ---- prep ----
// wip: K=16 A-frags (8*Wi, z col at dead diag slot), frag idx i*8+kt*4+fo
// w1p/w2p: MX K=64 A-frags (8*W): frag f=fo*2+f2, lane l, byte j:
//          row=fo*32+(l&31), k=f2*64+(l>>5)*32+j
// wfp: MX A-frags of 64*wf, row0 only: frag f=i*2+f2
// bi8=8*bi, b1s=64*b1, b2s=512*b2, Mt=M^T
__global__ void prep(const float* __restrict__ Wi, const float* __restrict__ bi,
                     const float* __restrict__ W1, const float* __restrict__ b1,
                     const float* __restrict__ W2, const float* __restrict__ b2,
                     const float* __restrict__ M,  const float* __restrict__ wf,
                     unsigned char* __restrict__ wip, unsigned char* __restrict__ w1p,
                     unsigned char* __restrict__ w2p, unsigned char* __restrict__ wfp,
                     float* __restrict__ Mt, float* __restrict__ bi8,
                     float* __restrict__ b1s, float* __restrict__ b2s){
  int b = (int)blockIdx.x;
  int l = (int)threadIdx.x;
  int h = l >> 5, cl = l & 31;
  if (b < 256){                       // wip (unchanged K=16 layout)
    int i = b >> 3, kt = (b >> 2) & 1, fo = b & 3;
    int row = fo*32 + cl;
    unsigned char bytes[8];
#pragma unroll
    for (int j = 0; j < 8; ++j){
      int k = kt*16 + h*8 + j;
      int src = (k == i) ? XD : k;
      bytes[j] = f2e4m3(8.f * Wi[((size_t)i*HD + row)*(XD+1) + src]);
    }
    long v8; __builtin_memcpy(&v8, bytes, 8);
    *(long*)(wip + ((size_t)b*64 + l)*8) = v8;
  } else if (b < 272){                // W1/W2 MX A-frags
    const float* W = (b < 264) ? W1 : W2;
    unsigned char* dp = (b < 264) ? w1p : w2p;
    int f = (b - 256) & 7;
    int fo = f >> 1, f2 = f & 1;
    int row = fo*32 + cl;
    union { unsigned char bt[32]; int4 v[2]; } u;
#pragma unroll
    for (int j = 0; j < 32; ++j)
      u.bt[j] = f2e4m3(8.f * W[(size_t)row*HD + f2*64 + h*32 + j]);
    *(int4*)(dp + ((size_t)f*64 + l)*32)      = u.v[0];
    *(int4*)(dp + ((size_t)f*64 + l)*32 + 16) = u.v[1];
  } else if (b < 336){                // wf MX A-frags (row 0 only)
    int f = b - 272;                  // i*2 + f2
    int i = f >> 1, f2 = f & 1;
    union { unsigned char bt[32]; int4 v[2]; } u;
#pragma unroll
    for (int j = 0; j < 32; ++j){
      float v = (cl == 0) ? 64.f * wf[(size_t)i*HD + f2*64 + h*32 + j] : 0.f;
      u.bt[j] = f2e4m3(v);
    }
    *(int4*)(wfp + ((size_t)f*64 + l)*32)      = u.v[0];
    *(int4*)(wfp + ((size_t)f*64 + l)*32 + 16) = u.v[1];
  } else if (b == 336){               // M transpose
#pragma unroll
    for (int t = 0; t < 16; ++t){
      int idx = t*64 + l;
      int i = idx >> 5, k = idx & 31;
      Mt[i*32 + k] = M[k*32 + i];
    }
  } else {                            // scaled biases
    for (int t = 0; t < 64; ++t){
      int idx = t*64 + l;
      bi8[idx] = 8.f * bi[idx];
    }
#pragma unroll
    for (int t = 0; t < 2; ++t){
      b1s[t*64 + l] = 64.f  * b1[t*64 + l];
      b2s[t*64 + l] = 512.f * b2[t*64 + l];
    }
  }
}

// pack one tile's x_masked B-frags (K=16 fp8 layout) from state, z spliced at k==i
static __device__ __forceinline__ void pack_xb(const float (&st)[16], const float (&mtv)[16],
                                               float zvv, int i, bool hm, long (&xb)[2]){
  int xbi[2][2];
#pragma unroll
  for (int kt = 0; kt < 2; ++kt)
#pragma unroll
    for (int d = 0; d < 2; ++d){
      float v0 = st[kt*8+4*d+0]*mtv[kt*8+4*d+0];
      float v1 = st[kt*8+4*d+1]*mtv[kt*8+4*d+1];
      float v2 = st[kt*8+4*d+2]*mtv[kt*8+4*d+2];
      float v3 = st[kt*8+4*d+3]*mtv[kt*8+4*d+3];
      int w = cvtpk_fp8<false>(v0, v1, 0);
      xbi[kt][d] = cvtpk_fp8<true>(v2, v3, w);
    }
  const int kti = i>>4, di = (i>>2)&1, sh = 8*(i&3);
  const int msk = ~(0xFF << sh);
  int pz = cvtpk_fp8<false>(zvv, 0.f, 0) & 0xFF;
  int ins = pz << sh;
#pragma unroll
  for (int kt = 0; kt < 2; ++kt)
#pragma unroll
    for (int d = 0; d < 2; ++d)
      if (kt == kti && d == di){
        int mod = (xbi[kt][d] & msk) | ins;
        xbi[kt][d] = hm ? mod : xbi[kt][d];
      }
#pragma unroll
  for (int kt = 0; kt < 2; ++kt)
    xb[kt] = (long)(((unsigned long)(unsigned)xbi[kt][0]) |
                    ((unsigned long)(unsigned)xbi[kt][1] << 32));
}

static __device__ __forceinline__ i32x8 ld_mx(const unsigned char* __restrict__ p){
  union { int4 h[2]; i32x8 v; } u;
  u.h[0] = *(const int4*)(p);
  u.h[1] = *(const int4*)(p + 16);
  return u.v;
}

// ---- main kernel: 1024 blocks x 64 threads; 2 batch tiles/wave lockstep; 1 wave/SIMD ----
// L1/L2/epilogue use MX-scaled K=64 fp8 MFMAs (2.4x less matrix-pipe time than K=16).
__global__ void __launch_bounds__(64, 1)
genkern(const float* __restrict__ x, const float* __restrict__ z,
        const float* __restrict__ bf,
        const unsigned char* __restrict__ wip, const unsigned char* __restrict__ w1p,
        const unsigned char* __restrict__ w2p, const unsigned char* __restrict__ wfp,
        const float* __restrict__ Mt, const float* __restrict__ bi8,
        const float* __restrict__ b1s, const float* __restrict__ b2s,
        float* __restrict__ out)
{
  const int lane = (int)threadIdx.x;
  const int half = lane >> 5, col = lane & 31;
  const long rbase = (long)blockIdx.x * 64;

  // resident MX weight frags: [fo][f2] (128 arch VGPRs total)
  i32x8 w1mx[4][2], w2mx[4][2];
#pragma unroll
  for (int fo = 0; fo < 4; ++fo)
#pragma unroll
    for (int f2 = 0; f2 < 2; ++f2){
      int f = fo*2 + f2;
      w1mx[fo][f2] = ld_mx(w1p + ((size_t)f*64 + lane)*32);
      w2mx[fo][f2] = ld_mx(w2p + ((size_t)f*64 + lane)*32);
    }

  // out-state per tile: lane(half h) holds k = kt*16 + h*8 + j at slot kt*8+j
  float stA[16], stB[16];
#pragma unroll
  for (int kt = 0; kt < 2; ++kt){
    ld8(x + (rbase + col)*XD + kt*16 + half*8,      &stA[kt*8]);
    ld8(x + (rbase + 32 + col)*XD + kt*16 + half*8, &stB[kt*8]);
  }

  // single-buffer next-step prefetch registers (loaded after last use each step)
  long wif[2][4];
  i32x8 wfx[2];
  float zA, zB;
#pragma unroll
  for (int kt = 0; kt < 2; ++kt)
#pragma unroll
    for (int fo = 0; fo < 4; ++fo)
      wif[kt][fo] = *(const long*)(wip + (((size_t)(kt*4 + fo))*64 + lane)*8);
  wfx[0] = ld_mx(wfp + ((size_t)0*64 + lane)*32);
  wfx[1] = ld_mx(wfp + ((size_t)1*64 + lane)*32);
  zA = z[(rbase + col)*XD + 0];
  zB = z[(rbase + 32 + col)*XD + 0];

#pragma unroll 1
  for (int i = 0; i < XD; ++i){
    const int ip = (i + 1) & (XD - 1);
    const bool hm = (half == ((i>>3)&1));
    const int slot_i = ((i>>4)<<3) | (i&7);
    const float bfv = bf[i];

    float mtv[16];
#pragma unroll
    for (int kt = 0; kt < 2; ++kt)
      ld8(Mt + i*32 + kt*16 + half*8, &mtv[kt*8]);

    long xbA[2], xbB[2];
    pack_xb(stA, mtv, zA, i, hm, xbA);
    pack_xb(stB, mtv, zB, i, hm, xbB);
    zA = z[(rbase + col)*XD + ip];        // next-step z (full-step latency cover)
    zB = z[(rbase + 32 + col)*XD + ip];

    // ---- input layer: K=32 via 2x K=16 fp8 MFMA, bias C-init ----
    f32x16 accA[4], accB[4];
#pragma unroll
    for (int fo = 0; fo < 4; ++fo){
      f32x16 bc = load_bias16(bi8 + (size_t)i*HD + fo*32, half);
      accA[fo] = __builtin_amdgcn_mfma_f32_32x32x16_fp8_fp8(wif[0][fo], xbA[0], bc, 0,0,0);
      accB[fo] = __builtin_amdgcn_mfma_f32_32x32x16_fp8_fp8(wif[0][fo], xbB[0], bc, 0,0,0);
    }
#pragma unroll
    for (int fo = 0; fo < 4; ++fo){
      accA[fo] = __builtin_amdgcn_mfma_f32_32x32x16_fp8_fp8(wif[1][fo], xbA[1], accA[fo], 0,0,0);
      accB[fo] = __builtin_amdgcn_mfma_f32_32x32x16_fp8_fp8(wif[1][fo], xbB[1], accB[fo], 0,0,0);
    }
    // prefetch next step's Wi frags (consumed next iteration; ~full step to land)
#pragma unroll
    for (int kt = 0; kt < 2; ++kt)
#pragma unroll
      for (int fo = 0; fo < 4; ++fo)
        wif[kt][fo] = *(const long*)(wip + (((size_t)(ip*8 + kt*4 + fo))*64 + lane)*8);

    // ---- layer 1: K=128 via 2 MX per fo ----
    {
      i32x8 mxA0 = c2mx(accA[0], accA[1]);
      i32x8 mxA1 = c2mx(accA[2], accA[3]);
      i32x8 mxB0 = c2mx(accB[0], accB[1]);
      i32x8 mxB1 = c2mx(accB[2], accB[3]);
#pragma unroll
      for (int fo = 0; fo < 4; ++fo){
        f32x16 bc = load_bias16(b1s + fo*32, half);
        accA[fo] = mfma_mx(w1mx[fo][0], mxA0, bc);
        accB[fo] = mfma_mx(w1mx[fo][0], mxB0, bc);
      }
#pragma unroll
      for (int fo = 0; fo < 4; ++fo){
        accA[fo] = mfma_mx(w1mx[fo][1], mxA1, accA[fo]);
        accB[fo] = mfma_mx(w1mx[fo][1], mxB1, accB[fo]);
      }
    }

    // ---- layer 2: K=128 via 2 MX per fo ----
    {
      i32x8 mxA0 = c2mx(accA[0], accA[1]);
      i32x8 mxA1 = c2mx(accA[2], accA[3]);
      i32x8 mxB0 = c2mx(accB[0], accB[1]);
      i32x8 mxB1 = c2mx(accB[2], accB[3]);
#pragma unroll
      for (int fo = 0; fo < 4; ++fo){
        f32x16 bc = load_bias16(b2s + fo*32, half);
        accA[fo] = mfma_mx(w2mx[fo][0], mxA0, bc);
        accB[fo] = mfma_mx(w2mx[fo][0], mxB0, bc);
      }
#pragma unroll
      for (int fo = 0; fo < 4; ++fo){
        accA[fo] = mfma_mx(w2mx[fo][1], mxA1, accA[fo]);
        accB[fo] = mfma_mx(w2mx[fo][1], mxB1, accB[fo]);
      }
    }

    // ---- epilogue: u = (64wf) . fp8(relu(512 h3)) via 2-chain MX; row 0 of D ----
    {
      i32x8 mxA0 = c2mx(accA[0], accA[1]);
      i32x8 mxA1 = c2mx(accA[2], accA[3]);
      i32x8 mxB0 = c2mx(accB[0], accB[1]);
      i32x8 mxB1 = c2mx(accB[2], accB[3]);
      f32x16 eA, eB;
#pragma unroll
      for (int q = 0; q < 16; ++q){ eA[q] = 0.f; eB[q] = 0.f; }
      eA = mfma_mx(wfx[0], mxA0, eA);
      eB = mfma_mx(wfx[0], mxB0, eB);
      eA = mfma_mx(wfx[1], mxA1, eA);
      eB = mfma_mx(wfx[1], mxB1, eB);
      float uA = eA[0], uB = eB[0];            // feat 0 lives in h0 lanes, elem 0
      float sA = __shfl_xor(uA, 32, 64);
      float sB = __shfl_xor(uB, 32, 64);
      float tA = half ? sA : uA;
      float tB = half ? sB : uB;
      float vA = 1.f/(1.f + __expf(-(tA*(1.f/32768.f) + bfv)));
      float vB = 1.f/(1.f + __expf(-(tB*(1.f/32768.f) + bfv)));
#pragma unroll
      for (int s = 0; s < 16; ++s)
        if (s == slot_i){
          stA[s] = hm ? vA : stA[s];
          stB[s] = hm ? vB : stB[s];
        }
    }
    // prefetch next step's wf frags
    wfx[0] = ld_mx(wfp + ((size_t)(ip*2 + 0)*64 + lane)*32);
    wfx[1] = ld_mx(wfp + ((size_t)(ip*2 + 1)*64 + lane)*32);
  }

  // write out both tiles
#pragma unroll
  for (int kt = 0; kt < 2; ++kt){
    float* pA = out + (rbase + col)*XD + kt*16 + half*8;
    float* pB = out + (rbase + 32 + col)*XD + kt*16 + half*8;
    float4 a, b;
    a.x = stA[kt*8+0]; a.y = stA[kt*8+1]; a.z = stA[kt*8+2]; a.w = stA[kt*8+3];
    b.x = stA[kt*8+4]; b.y = stA[kt*8+5]; b.z = stA[kt*8+6]; b.w = stA[kt*8+7];
    *(float4*)pA = a; *(float4*)(pA+4) = b;
    a.x = stB[kt*8+0]; a.y = stB[kt*8+1]; a.z = stB[kt*8+2]; a.w = stB[kt*8+3];
    b.x = stB[kt*8+4]; b.y = stB[kt*8+5]; b.z = stB[kt*8+6]; b.w = stB[kt*8+7];
    *(float4*)pB = a; *(float4*)(pB+4) = b;
  }
}

extern "C" void kernel_launch(void* const* d_in, const int* in_sizes, int n_in,
                              void* d_out, int out_size, void* d_ws, size_t ws_size,
                              hipStream_t stream){
  (void)in_sizes; (void)n_in; (void)out_size; (void)ws_size;
  const float* x  = (const float*)d_in[0];
  const float* z  = (const float*)d_in[1];
  const float* M  = (const float*)d_in[2];
  const float* Wi = (const float*)d_in[3];
  const float* bi = (const float*)d_in[4];
  const float* wf = (const float*)d_in[5];
  const float* bf = (const float*)d_in[6];
  const float* W1 = (const float*)d_in[7];
  const float* b1 = (const float*)d_in[8];
  const float* W2 = (const float*)d_in[9];
  const float* b2 = (const float*)d_in[10];

  unsigned char* wip = (unsigned char*)d_ws;            // 256*512 = 131072
  unsigned char* w1p = wip + 131072;                    // 8*64*32 = 16384
  unsigned char* w2p = w1p + 16384;                     // 16384
  unsigned char* wfp = w2p + 16384;                     // 64*64*32 = 131072
  float*         Mt  = (float*)(wfp + 131072);          // 4096
  float*         bi8 = Mt + 1024;                       // 16384
  float*         b1s = bi8 + 4096;                      // 512
  float*         b2s = b1s + 128;                       // 512

  prep<<<dim3(338), dim3(64), 0, stream>>>(Wi, bi, W1, b1, W2, b2, M, wf,
                                           wip, w1p, w2p, wfp, Mt, bi8, b1s, b2s);
  genkern<<<dim3(1024), dim3(64), 0, stream>>>(x, z, bf, wip, w1p, w2p, wfp, Mt,
                                               bi8, b1s, b2s, (float*)d_out);
}